// Round 1
// baseline (303.124 us; speedup 1.0000x reference)
//
#include <hip/hip_runtime.h>
#include <math.h>

#define Cdim 512
#define CRdim 32
#define Ldim 4096
#define Bdim 64

// ---------------- Kernel 1: per-(b,c) mean over L ----------------
__global__ __launch_bounds__(256) void se_reduce(const float* __restrict__ x,
                                                 float* __restrict__ mean) {
    const int row = blockIdx.x;               // b*C + c, 0..32767
    const float4* xr = reinterpret_cast<const float4*>(x + (size_t)row * Ldim);
    const int t = threadIdx.x;                // 256 threads, 1024 float4 per row
    float s = 0.0f;
#pragma unroll
    for (int k = 0; k < 4; ++k) {
        float4 v = xr[t + k * 256];
        s += (v.x + v.y) + (v.z + v.w);
    }
    // wave (64-lane) reduce
#pragma unroll
    for (int off = 32; off > 0; off >>= 1) s += __shfl_down(s, off, 64);
    __shared__ float wsum[4];
    if ((t & 63) == 0) wsum[t >> 6] = s;
    __syncthreads();
    if (t == 0) {
        float tot = (wsum[0] + wsum[1]) + (wsum[2] + wsum[3]);
        mean[row] = tot * (1.0f / Ldim);
    }
}

// ---------------- Kernel 2: tiny MLP (relu -> sigmoid) ----------------
__global__ __launch_bounds__(512) void se_mlp(const float* __restrict__ mean,
                                              const float* __restrict__ w1,
                                              const float* __restrict__ b1,
                                              const float* __restrict__ w2,
                                              const float* __restrict__ b2,
                                              float* __restrict__ scale) {
    const int b = blockIdx.x;                 // 0..63
    const int t = threadIdx.x;                // 512 threads
    __shared__ float m[Cdim];
    __shared__ float h[CRdim];
    m[t] = mean[b * Cdim + t];
    __syncthreads();
    if (t < CRdim) {
        float acc = b1[t];
        const float* w1r = w1 + t * Cdim;
#pragma unroll 8
        for (int c = 0; c < Cdim; ++c) acc = fmaf(m[c], w1r[c], acc);
        h[t] = fmaxf(acc, 0.0f);
    }
    __syncthreads();
    float acc = b2[t];
    const float* w2r = w2 + t * CRdim;
#pragma unroll
    for (int r = 0; r < CRdim; ++r) acc = fmaf(h[r], w2r[r], acc);
    scale[b * Cdim + t] = 1.0f / (1.0f + expf(-acc));
}

// ---------------- Kernel 3: out = x * s[b,c] ----------------
__global__ __launch_bounds__(256) void se_scale(const float* __restrict__ x,
                                                const float* __restrict__ scale,
                                                float* __restrict__ out) {
    const int row = blockIdx.x;               // b*C + c
    const float s = scale[row];
    const float4* xr = reinterpret_cast<const float4*>(x + (size_t)row * Ldim);
    float4* orow = reinterpret_cast<float4*>(out + (size_t)row * Ldim);
    const int t = threadIdx.x;
#pragma unroll
    for (int k = 0; k < 4; ++k) {
        float4 v = xr[t + k * 256];
        v.x *= s; v.y *= s; v.z *= s; v.w *= s;
        orow[t + k * 256] = v;
    }
}

extern "C" void kernel_launch(void* const* d_in, const int* in_sizes, int n_in,
                              void* d_out, int out_size, void* d_ws, size_t ws_size,
                              hipStream_t stream) {
    const float* x  = (const float*)d_in[0];
    const float* w1 = (const float*)d_in[1];
    const float* b1 = (const float*)d_in[2];
    const float* w2 = (const float*)d_in[3];
    const float* b2 = (const float*)d_in[4];
    float* out = (float*)d_out;

    float* mean  = (float*)d_ws;                         // 64*512 floats = 128 KB
    float* scale = mean + (size_t)Bdim * Cdim;           // next 128 KB

    const int nrows = Bdim * Cdim;                       // 32768
    se_reduce<<<nrows, 256, 0, stream>>>(x, mean);
    se_mlp<<<Bdim, Cdim, 0, stream>>>(mean, w1, b1, w2, b2, scale);
    se_scale<<<nrows, 256, 0, stream>>>(x, scale, out);
}

// Round 3
// 265.647 us; speedup vs baseline: 1.1411x; 1.1411x over previous
//
#include <hip/hip_runtime.h>
#include <math.h>

#define Cdim 512
#define CRdim 32
#define Ldim 4096
#define Bdim 64

typedef float f32x4 __attribute__((ext_vector_type(4)));

// ---------------- Kernel 1: per-(b,c) mean over L ----------------
// Ascending row order: leaves the TAIL of x resident in the 256 MiB L3.
__global__ __launch_bounds__(256) void se_reduce(const float* __restrict__ x,
                                                 float* __restrict__ mean) {
    const int row = blockIdx.x;               // b*C + c, 0..32767
    const f32x4* xr = reinterpret_cast<const f32x4*>(x + (size_t)row * Ldim);
    const int t = threadIdx.x;                // 256 threads, 1024 float4 per row
    float s = 0.0f;
#pragma unroll
    for (int k = 0; k < 4; ++k) {
        f32x4 v = xr[t + k * 256];
        s += (v.x + v.y) + (v.z + v.w);
    }
#pragma unroll
    for (int off = 32; off > 0; off >>= 1) s += __shfl_down(s, off, 64);
    __shared__ float wsum[4];
    if ((t & 63) == 0) wsum[t >> 6] = s;
    __syncthreads();
    if (t == 0) {
        float tot = (wsum[0] + wsum[1]) + (wsum[2] + wsum[3]);
        mean[row] = tot * (1.0f / Ldim);
    }
}

// ---------------- Kernel 2: tiny MLP (relu -> sigmoid) ----------------
__global__ __launch_bounds__(512) void se_mlp(const float* __restrict__ mean,
                                              const float* __restrict__ w1,
                                              const float* __restrict__ b1,
                                              const float* __restrict__ w2,
                                              const float* __restrict__ b2,
                                              float* __restrict__ scale) {
    const int b = blockIdx.x;                 // 0..63
    const int t = threadIdx.x;                // 512 threads
    __shared__ float m[Cdim];
    __shared__ float h[CRdim];
    m[t] = mean[b * Cdim + t];
    __syncthreads();
    if (t < CRdim) {
        float acc = b1[t];
        const float* w1r = w1 + t * Cdim;
#pragma unroll 8
        for (int c = 0; c < Cdim; ++c) acc = fmaf(m[c], w1r[c], acc);
        h[t] = fmaxf(acc, 0.0f);
    }
    __syncthreads();
    float acc = b2[t];
    const float* w2r = w2 + t * CRdim;
#pragma unroll
    for (int r = 0; r < CRdim; ++r) acc = fmaf(h[r], w2r[r], acc);
    scale[b * Cdim + t] = 1.0f / (1.0f + expf(-acc));
}

// ---------------- Kernel 3: out = x * s[b,c] ----------------
// DESCENDING row order: consumes the L3-resident tail of x first.
// Non-temporal stores: keep the 512 MiB output stream out of L2/L3 so it
// doesn't evict the x lines we want to hit.
__global__ __launch_bounds__(256) void se_scale(const float* __restrict__ x,
                                                const float* __restrict__ scale,
                                                float* __restrict__ out) {
    const int row = (Bdim * Cdim - 1) - blockIdx.x;      // reversed traversal
    const float s = scale[row];
    const f32x4* xr = reinterpret_cast<const f32x4*>(x + (size_t)row * Ldim);
    f32x4* orow = reinterpret_cast<f32x4*>(out + (size_t)row * Ldim);
    const int t = threadIdx.x;
#pragma unroll
    for (int k = 0; k < 4; ++k) {
        f32x4 v = xr[t + k * 256];
        v *= s;
        __builtin_nontemporal_store(v, &orow[t + k * 256]);
    }
}

extern "C" void kernel_launch(void* const* d_in, const int* in_sizes, int n_in,
                              void* d_out, int out_size, void* d_ws, size_t ws_size,
                              hipStream_t stream) {
    const float* x  = (const float*)d_in[0];
    const float* w1 = (const float*)d_in[1];
    const float* b1 = (const float*)d_in[2];
    const float* w2 = (const float*)d_in[3];
    const float* b2 = (const float*)d_in[4];
    float* out = (float*)d_out;

    float* mean  = (float*)d_ws;                         // 64*512 floats = 128 KB
    float* scale = mean + (size_t)Bdim * Cdim;           // next 128 KB

    const int nrows = Bdim * Cdim;                       // 32768
    se_reduce<<<nrows, 256, 0, stream>>>(x, mean);
    se_mlp<<<Bdim, Cdim, 0, stream>>>(mean, w1, b1, w2, b2, scale);
    se_scale<<<nrows, 256, 0, stream>>>(x, scale, out);
}